// Round 1
// baseline (2197.093 us; speedup 1.0000x reference)
//
#include <hip/hip_runtime.h>
#include <hip/hip_bf16.h>
#include <math.h>

#define D_MODEL 1024
#define STATE 64
#define HEADS 8
#define INNER 2048
#define HEAD_DIM 256
#define PROJ_OUT 4232   // 2*INNER + 2*STATE + HEADS
#define BATCH 2
#define SEQ 1024
#define NROWS (BATCH*SEQ)
#define EPS 1e-5f

// ---------------- LayerNorm: one block per row ----------------
__global__ __launch_bounds__(256) void ln_kernel(
    const float* __restrict__ x, const float* __restrict__ gamma,
    const float* __restrict__ beta, float* __restrict__ out)
{
    int row = blockIdx.x;
    int tid = threadIdx.x;
    const float4* xr = (const float4*)(x + (size_t)row * D_MODEL);
    float4 v = xr[tid];
    float s  = v.x + v.y + v.z + v.w;
    float sq = v.x*v.x + v.y*v.y + v.z*v.z + v.w*v.w;
    #pragma unroll
    for (int off = 32; off > 0; off >>= 1) {
        s  += __shfl_down(s,  off, 64);
        sq += __shfl_down(sq, off, 64);
    }
    __shared__ float ls[4], lq[4];
    int wave = tid >> 6, lane = tid & 63;
    if (lane == 0) { ls[wave] = s; lq[wave] = sq; }
    __syncthreads();
    s  = ls[0] + ls[1] + ls[2] + ls[3];
    sq = lq[0] + lq[1] + lq[2] + lq[3];
    float mu  = s * (1.f / D_MODEL);
    float var = sq * (1.f / D_MODEL) - mu * mu;
    float rs  = rsqrtf(var + EPS);
    float4 g  = ((const float4*)gamma)[tid];
    float4 bb = ((const float4*)beta)[tid];
    float4 o;
    o.x = (v.x - mu) * rs * g.x + bb.x;
    o.y = (v.y - mu) * rs * g.y + bb.y;
    o.z = (v.z - mu) * rs * g.z + bb.z;
    o.w = (v.w - mu) * rs * g.w + bb.w;
    ((float4*)(out + (size_t)row * D_MODEL))[tid] = o;
}

// ---------------- fp32 tiled GEMM: C = A@B + bias (+ add) ----------------
// A: MxK row-major, B: KxN row-major. 64x64 tile, K-step 16, 256 threads,
// 4x4 micro-tile per thread. M, K multiples of 64/16; N guarded.
template<bool HAS_ADD>
__global__ __launch_bounds__(256) void gemm_f32(
    const float* __restrict__ A, const float* __restrict__ B,
    const float* __restrict__ bias, const float* __restrict__ add,
    float* __restrict__ C, int M, int N, int K)
{
    __shared__ float As[16][68];   // [k][m], pad 4 keeps rows 16B-aligned
    __shared__ float Bs[16][68];   // [k][n]
    int tid = threadIdx.x;
    int tx = tid & 15, ty = tid >> 4;
    int n0 = blockIdx.x * 64;
    int m0 = blockIdx.y * 64;

    float acc[4][4] = {};

    int am = tid >> 2;          // 0..63 (row within A tile)
    int ak = (tid & 3) * 4;     // 0,4,8,12 (k within tile)
    int bk = tid >> 4;          // 0..15
    int bn = (tid & 15) * 4;    // 0..60

    for (int k0 = 0; k0 < K; k0 += 16) {
        float4 av = *(const float4*)(A + (size_t)(m0 + am) * K + k0 + ak);
        As[ak + 0][am] = av.x; As[ak + 1][am] = av.y;
        As[ak + 2][am] = av.z; As[ak + 3][am] = av.w;
        int gcol = n0 + bn;
        float4 bv;
        if (gcol + 3 < N) bv = *(const float4*)(B + (size_t)(k0 + bk) * N + gcol);
        else              bv = make_float4(0.f, 0.f, 0.f, 0.f);
        *(float4*)&Bs[bk][bn] = bv;
        __syncthreads();
        #pragma unroll
        for (int k = 0; k < 16; ++k) {
            float4 a = *(const float4*)&As[k][ty * 4];
            float4 b = *(const float4*)&Bs[k][tx * 4];
            float ar[4] = {a.x, a.y, a.z, a.w};
            float br_[4] = {b.x, b.y, b.z, b.w};
            #pragma unroll
            for (int i = 0; i < 4; ++i)
                #pragma unroll
                for (int j = 0; j < 4; ++j)
                    acc[i][j] += ar[i] * br_[j];
        }
        __syncthreads();
    }

    #pragma unroll
    for (int i = 0; i < 4; ++i) {
        int r = m0 + ty * 4 + i;
        #pragma unroll
        for (int j = 0; j < 4; ++j) {
            int c = n0 + tx * 4 + j;
            if (c < N) {
                float v = acc[i][j] + bias[c];
                if (HAS_ADD) v += add[(size_t)r * N + c];
                C[(size_t)r * N + c] = v;
            }
        }
    }
}

// ---------------- sequential scan: one block per (b,h), thread = p ----------------
// h-state [p][64] lives in registers. B/C/dt rows are wave-uniform -> scalar loads.
// Writes gated y: yg[row][h*256+p] = (scan_y + D*x) * silu(z)
__global__ __launch_bounds__(256) void scan_kernel(
    const float* __restrict__ zx,      // [NROWS][PROJ_OUT]
    const float* __restrict__ A_log, const float* __restrict__ D_skip,
    const float* __restrict__ dt_bias,
    float* __restrict__ yg)            // [NROWS][INNER]
{
    int bh = blockIdx.x;               // 0..15
    int b  = bh >> 3, h = bh & 7;
    int p  = threadIdx.x;              // 0..255
    float a   = -expf(A_log[h]);
    float dsk = D_skip[h];
    float dtb = dt_bias[h];

    float hs[STATE];
    #pragma unroll
    for (int n = 0; n < STATE; ++n) hs[n] = 0.f;

    for (int t = 0; t < SEQ; ++t) {
        const float* row = zx + (size_t)(b * SEQ + t) * PROJ_OUT;
        float dtr = row[2 * INNER + 2 * STATE + h] + dtb;
        float dt  = (dtr > 20.f) ? dtr : log1pf(expf(dtr));
        float dec = expf(dt * a);
        float x   = row[INNER + h * HEAD_DIM + p];
        float z   = row[h * HEAD_DIM + p];
        float dtx = dt * x;

        #pragma unroll
        for (int n = 0; n < STATE; ++n) {
            float Bv = row[2 * INNER + n];
            hs[n] = dec * hs[n] + dtx * Bv;
        }
        float y0 = 0.f, y1 = 0.f, y2 = 0.f, y3 = 0.f;
        #pragma unroll
        for (int n = 0; n < STATE; n += 4) {
            y0 += hs[n + 0] * row[2 * INNER + STATE + n + 0];
            y1 += hs[n + 1] * row[2 * INNER + STATE + n + 1];
            y2 += hs[n + 2] * row[2 * INNER + STATE + n + 2];
            y3 += hs[n + 3] * row[2 * INNER + STATE + n + 3];
        }
        float y = (y0 + y1) + (y2 + y3) + dsk * x;
        float gate = z / (1.f + expf(-z));
        yg[(size_t)(b * SEQ + t) * INNER + h * HEAD_DIM + p] = y * gate;
    }
}

extern "C" void kernel_launch(void* const* d_in, const int* in_sizes, int n_in,
                              void* d_out, int out_size, void* d_ws, size_t ws_size,
                              hipStream_t stream) {
    const float* input  = (const float*)d_in[0];
    const float* gamma  = (const float*)d_in[1];
    const float* beta   = (const float*)d_in[2];
    const float* W_in   = (const float*)d_in[3];
    const float* b_in   = (const float*)d_in[4];
    const float* A_log  = (const float*)d_in[5];
    const float* D_skip = (const float*)d_in[6];
    const float* dt_b   = (const float*)d_in[7];
    const float* W_out  = (const float*)d_in[8];
    const float* b_out  = (const float*)d_in[9];
    float* out = (float*)d_out;

    char* ws = (char*)d_ws;
    float* normed = (float*)ws;
    float* zx     = (float*)(ws + (size_t)NROWS * D_MODEL * 4);
    float* yg     = (float*)(ws + (size_t)NROWS * D_MODEL * 4
                                + (size_t)NROWS * PROJ_OUT * 4);

    ln_kernel<<<NROWS, 256, 0, stream>>>(input, gamma, beta, normed);

    dim3 g1((PROJ_OUT + 63) / 64, NROWS / 64);
    gemm_f32<false><<<g1, 256, 0, stream>>>(normed, W_in, b_in, nullptr, zx,
                                            NROWS, PROJ_OUT, D_MODEL);

    scan_kernel<<<BATCH * HEADS, 256, 0, stream>>>(zx, A_log, D_skip, dt_b, yg);

    dim3 g2(D_MODEL / 64, NROWS / 64);
    gemm_f32<true><<<g2, 256, 0, stream>>>(yg, W_out, b_out, input, out,
                                           NROWS, D_MODEL, INNER);
}

// Round 2
// 594.533 us; speedup vs baseline: 3.6955x; 3.6955x over previous
//
#include <hip/hip_runtime.h>
#include <hip/hip_bf16.h>
#include <math.h>

#define D_MODEL 1024
#define STATE 64
#define HEADS 8
#define INNER 2048
#define HEAD_DIM 256
#define PROJ_OUT 4232   // 2*INNER + 2*STATE + HEADS
#define BATCH 2
#define SEQ 1024
#define NROWS (BATCH*SEQ)
#define EPS 1e-5f

#define QCHUNK 64
#define NCH (SEQ / QCHUNK)      // 16 chunks
#define BH (BATCH * HEADS)      // 16

// ---------------- LayerNorm: one block per row ----------------
__global__ __launch_bounds__(256) void ln_kernel(
    const float* __restrict__ x, const float* __restrict__ gamma,
    const float* __restrict__ beta, float* __restrict__ out)
{
    int row = blockIdx.x;
    int tid = threadIdx.x;
    const float4* xr = (const float4*)(x + (size_t)row * D_MODEL);
    float4 v = xr[tid];
    float s  = v.x + v.y + v.z + v.w;
    float sq = v.x*v.x + v.y*v.y + v.z*v.z + v.w*v.w;
    #pragma unroll
    for (int off = 32; off > 0; off >>= 1) {
        s  += __shfl_down(s,  off, 64);
        sq += __shfl_down(sq, off, 64);
    }
    __shared__ float ls[4], lq[4];
    int wave = tid >> 6, lane = tid & 63;
    if (lane == 0) { ls[wave] = s; lq[wave] = sq; }
    __syncthreads();
    s  = ls[0] + ls[1] + ls[2] + ls[3];
    sq = lq[0] + lq[1] + lq[2] + lq[3];
    float mu  = s * (1.f / D_MODEL);
    float var = sq * (1.f / D_MODEL) - mu * mu;
    float rs  = rsqrtf(var + EPS);
    float4 g  = ((const float4*)gamma)[tid];
    float4 bb = ((const float4*)beta)[tid];
    float4 o;
    o.x = (v.x - mu) * rs * g.x + bb.x;
    o.y = (v.y - mu) * rs * g.y + bb.y;
    o.z = (v.z - mu) * rs * g.z + bb.z;
    o.w = (v.w - mu) * rs * g.w + bb.w;
    ((float4*)(out + (size_t)row * D_MODEL))[tid] = o;
}

// ---------------- fp32 tiled GEMM: C = A@B + bias (+ add) ----------------
template<bool HAS_ADD>
__global__ __launch_bounds__(256) void gemm_f32(
    const float* __restrict__ A, const float* __restrict__ B,
    const float* __restrict__ bias, const float* __restrict__ add,
    float* __restrict__ C, int M, int N, int K)
{
    __shared__ float As[16][68];
    __shared__ float Bs[16][68];
    int tid = threadIdx.x;
    int tx = tid & 15, ty = tid >> 4;
    int n0 = blockIdx.x * 64;
    int m0 = blockIdx.y * 64;

    float acc[4][4] = {};

    int am = tid >> 2;
    int ak = (tid & 3) * 4;
    int bk = tid >> 4;
    int bn = (tid & 15) * 4;

    for (int k0 = 0; k0 < K; k0 += 16) {
        float4 av = *(const float4*)(A + (size_t)(m0 + am) * K + k0 + ak);
        As[ak + 0][am] = av.x; As[ak + 1][am] = av.y;
        As[ak + 2][am] = av.z; As[ak + 3][am] = av.w;
        int gcol = n0 + bn;
        float4 bv;
        if (gcol + 3 < N) bv = *(const float4*)(B + (size_t)(k0 + bk) * N + gcol);
        else              bv = make_float4(0.f, 0.f, 0.f, 0.f);
        *(float4*)&Bs[bk][bn] = bv;
        __syncthreads();
        #pragma unroll
        for (int k = 0; k < 16; ++k) {
            float4 a = *(const float4*)&As[k][ty * 4];
            float4 b = *(const float4*)&Bs[k][tx * 4];
            float ar[4] = {a.x, a.y, a.z, a.w};
            float br_[4] = {b.x, b.y, b.z, b.w};
            #pragma unroll
            for (int i = 0; i < 4; ++i)
                #pragma unroll
                for (int j = 0; j < 4; ++j)
                    acc[i][j] += ar[i] * br_[j];
        }
        __syncthreads();
    }

    #pragma unroll
    for (int i = 0; i < 4; ++i) {
        int r = m0 + ty * 4 + i;
        #pragma unroll
        for (int j = 0; j < 4; ++j) {
            int c = n0 + tx * 4 + j;
            if (c < N) {
                float v = acc[i][j] + bias[c];
                if (HAS_ADD) v += add[(size_t)r * N + c];
                C[(size_t)r * N + c] = v;
            }
        }
    }
}

// ================= chunked scan =================
// Pass 1: each block = (bh, chunk). Scan chunk from h=0, write local state
// S[bh][ck][n][p] and scalar decay product Dk[bh][ck].
__global__ __launch_bounds__(256) void scan_pass1(
    const float* __restrict__ zx, const float* __restrict__ A_log,
    const float* __restrict__ dt_bias,
    float* __restrict__ Sbuf, float* __restrict__ Dk)
{
    int blk = blockIdx.x;
    int bh = blk / NCH, ck = blk % NCH;
    int b = bh >> 3, h = bh & 7;
    int p = threadIdx.x;
    float a   = -expf(A_log[h]);
    float dtb = dt_bias[h];

    float hs[STATE];
    #pragma unroll
    for (int n = 0; n < STATE; ++n) hs[n] = 0.f;
    float dtsum = 0.f;

    int t0 = ck * QCHUNK;
    for (int tt = 0; tt < QCHUNK; ++tt) {
        const float* row = zx + (size_t)(b * SEQ + t0 + tt) * PROJ_OUT;
        float dtr = row[2 * INNER + 2 * STATE + h] + dtb;
        float dt  = (dtr > 20.f) ? dtr : log1pf(expf(dtr));
        float dec = expf(dt * a);
        dtsum += dt;
        float x   = row[INNER + h * HEAD_DIM + p];
        float dtx = dt * x;
        #pragma unroll
        for (int n = 0; n < STATE; ++n)
            hs[n] = dec * hs[n] + dtx * row[2 * INNER + n];
    }
    float* sp = Sbuf + ((size_t)bh * NCH + ck) * (STATE * HEAD_DIM);
    #pragma unroll
    for (int n = 0; n < STATE; ++n)
        sp[n * HEAD_DIM + p] = hs[n];
    if (p == 0) Dk[bh * NCH + ck] = expf(dtsum * a);
}

// Combine: per (bh, element e in [0,16384)): serial scan over chunks,
// rewriting S[k] in place with the chunk-START state.
__global__ __launch_bounds__(256) void scan_combine(
    float* __restrict__ Sbuf, const float* __restrict__ Dk)
{
    int bh = blockIdx.y;
    int e  = blockIdx.x * 256 + threadIdx.x;    // 0..16383
    size_t base = (size_t)bh * NCH * (STATE * HEAD_DIM) + e;
    float h = 0.f;
    #pragma unroll
    for (int k = 0; k < NCH; ++k) {
        size_t idx = base + (size_t)k * (STATE * HEAD_DIM);
        float s = Sbuf[idx];
        Sbuf[idx] = h;
        h = Dk[bh * NCH + k] * h + s;
    }
}

// Pass 2: re-scan each chunk from its true start state, emit gated y.
__global__ __launch_bounds__(256) void scan_pass2(
    const float* __restrict__ zx, const float* __restrict__ A_log,
    const float* __restrict__ D_skip, const float* __restrict__ dt_bias,
    const float* __restrict__ Sbuf, float* __restrict__ yg)
{
    int blk = blockIdx.x;
    int bh = blk / NCH, ck = blk % NCH;
    int b = bh >> 3, h = bh & 7;
    int p = threadIdx.x;
    float a   = -expf(A_log[h]);
    float dsk = D_skip[h];
    float dtb = dt_bias[h];

    const float* sp = Sbuf + ((size_t)bh * NCH + ck) * (STATE * HEAD_DIM);
    float hs[STATE];
    #pragma unroll
    for (int n = 0; n < STATE; ++n) hs[n] = sp[n * HEAD_DIM + p];

    int t0 = ck * QCHUNK;
    for (int tt = 0; tt < QCHUNK; ++tt) {
        const float* row = zx + (size_t)(b * SEQ + t0 + tt) * PROJ_OUT;
        float dtr = row[2 * INNER + 2 * STATE + h] + dtb;
        float dt  = (dtr > 20.f) ? dtr : log1pf(expf(dtr));
        float dec = expf(dt * a);
        float x   = row[INNER + h * HEAD_DIM + p];
        float z   = row[h * HEAD_DIM + p];
        float dtx = dt * x;

        #pragma unroll
        for (int n = 0; n < STATE; ++n)
            hs[n] = dec * hs[n] + dtx * row[2 * INNER + n];

        float y0 = 0.f, y1 = 0.f, y2 = 0.f, y3 = 0.f;
        #pragma unroll
        for (int n = 0; n < STATE; n += 4) {
            y0 += hs[n + 0] * row[2 * INNER + STATE + n + 0];
            y1 += hs[n + 1] * row[2 * INNER + STATE + n + 1];
            y2 += hs[n + 2] * row[2 * INNER + STATE + n + 2];
            y3 += hs[n + 3] * row[2 * INNER + STATE + n + 3];
        }
        float y = (y0 + y1) + (y2 + y3) + dsk * x;
        float gate = z / (1.f + expf(-z));
        yg[(size_t)(b * SEQ + t0 + tt) * INNER + h * HEAD_DIM + p] = y * gate;
    }
}

// ---------------- fallback serial scan (if ws too small) ----------------
__global__ __launch_bounds__(256) void scan_kernel(
    const float* __restrict__ zx,
    const float* __restrict__ A_log, const float* __restrict__ D_skip,
    const float* __restrict__ dt_bias,
    float* __restrict__ yg)
{
    int bh = blockIdx.x;
    int b  = bh >> 3, h = bh & 7;
    int p  = threadIdx.x;
    float a   = -expf(A_log[h]);
    float dsk = D_skip[h];
    float dtb = dt_bias[h];

    float hs[STATE];
    #pragma unroll
    for (int n = 0; n < STATE; ++n) hs[n] = 0.f;

    for (int t = 0; t < SEQ; ++t) {
        const float* row = zx + (size_t)(b * SEQ + t) * PROJ_OUT;
        float dtr = row[2 * INNER + 2 * STATE + h] + dtb;
        float dt  = (dtr > 20.f) ? dtr : log1pf(expf(dtr));
        float dec = expf(dt * a);
        float x   = row[INNER + h * HEAD_DIM + p];
        float z   = row[h * HEAD_DIM + p];
        float dtx = dt * x;
        #pragma unroll
        for (int n = 0; n < STATE; ++n)
            hs[n] = dec * hs[n] + dtx * row[2 * INNER + n];
        float y0 = 0.f, y1 = 0.f, y2 = 0.f, y3 = 0.f;
        #pragma unroll
        for (int n = 0; n < STATE; n += 4) {
            y0 += hs[n + 0] * row[2 * INNER + STATE + n + 0];
            y1 += hs[n + 1] * row[2 * INNER + STATE + n + 1];
            y2 += hs[n + 2] * row[2 * INNER + STATE + n + 2];
            y3 += hs[n + 3] * row[2 * INNER + STATE + n + 3];
        }
        float y = (y0 + y1) + (y2 + y3) + dsk * x;
        float gate = z / (1.f + expf(-z));
        yg[(size_t)(b * SEQ + t) * INNER + h * HEAD_DIM + p] = y * gate;
    }
}

extern "C" void kernel_launch(void* const* d_in, const int* in_sizes, int n_in,
                              void* d_out, int out_size, void* d_ws, size_t ws_size,
                              hipStream_t stream) {
    const float* input  = (const float*)d_in[0];
    const float* gamma  = (const float*)d_in[1];
    const float* beta   = (const float*)d_in[2];
    const float* W_in   = (const float*)d_in[3];
    const float* b_in   = (const float*)d_in[4];
    const float* A_log  = (const float*)d_in[5];
    const float* D_skip = (const float*)d_in[6];
    const float* dt_b   = (const float*)d_in[7];
    const float* W_out  = (const float*)d_in[8];
    const float* b_out  = (const float*)d_in[9];
    float* out = (float*)d_out;

    char* ws = (char*)d_ws;
    size_t off = 0;
    float* normed = (float*)(ws + off); off += (size_t)NROWS * D_MODEL * 4;
    float* zx     = (float*)(ws + off); off += (size_t)NROWS * PROJ_OUT * 4;
    float* yg     = (float*)(ws + off); off += (size_t)NROWS * INNER * 4;
    float* Sbuf   = (float*)(ws + off); off += (size_t)BH * NCH * STATE * HEAD_DIM * 4;
    float* Dk     = (float*)(ws + off); off += (size_t)BH * NCH * 4;
    bool chunked = (off <= ws_size);

    ln_kernel<<<NROWS, 256, 0, stream>>>(input, gamma, beta, normed);

    dim3 g1((PROJ_OUT + 63) / 64, NROWS / 64);
    gemm_f32<false><<<g1, 256, 0, stream>>>(normed, W_in, b_in, nullptr, zx,
                                            NROWS, PROJ_OUT, D_MODEL);

    if (chunked) {
        scan_pass1<<<BH * NCH, 256, 0, stream>>>(zx, A_log, dt_b, Sbuf, Dk);
        dim3 gc(STATE * HEAD_DIM / 256, BH);
        scan_combine<<<gc, 256, 0, stream>>>(Sbuf, Dk);
        scan_pass2<<<BH * NCH, 256, 0, stream>>>(zx, A_log, D_skip, dt_b, Sbuf, yg);
    } else {
        scan_kernel<<<BH, 256, 0, stream>>>(zx, A_log, D_skip, dt_b, yg);
    }

    dim3 g2(D_MODEL / 64, NROWS / 64);
    gemm_f32<true><<<g2, 256, 0, stream>>>(yg, W_out, b_out, input, out,
                                           NROWS, D_MODEL, INNER);
}

// Round 3
// 300.229 us; speedup vs baseline: 7.3181x; 1.9803x over previous
//
#include <hip/hip_runtime.h>
#include <math.h>

#define D_MODEL 1024
#define STATE 64
#define HEADS 8
#define INNER 2048
#define HEAD_DIM 256
#define PROJ_OUT 4232   // 2*INNER + 2*STATE + HEADS
#define NPAD 4352       // 34*128
#define BATCH 2
#define SEQ 1024
#define NROWS (BATCH*SEQ)
#define EPS 1e-5f

#define QCHUNK 64
#define NCH (SEQ / QCHUNK)      // 16
#define BH (BATCH * HEADS)      // 16

typedef short s16x8 __attribute__((ext_vector_type(8)));
typedef float f32x4 __attribute__((ext_vector_type(4)));

#define LDS_AS(p) ((__attribute__((address_space(3))) void*)(p))
#define GLB_AS(p) ((const __attribute__((address_space(1))) void*)(p))

__device__ inline unsigned short f2bf(float f) {
    unsigned int u = __float_as_uint(f);
    unsigned int r = (u + 0x7fffu + ((u >> 16) & 1u)) >> 16;
    return (unsigned short)r;
}

// ---------------- LayerNorm -> bf16 ----------------
__global__ __launch_bounds__(256) void ln_kernel(
    const float* __restrict__ x, const float* __restrict__ gamma,
    const float* __restrict__ beta, unsigned short* __restrict__ out)
{
    int row = blockIdx.x;
    int tid = threadIdx.x;
    const float4* xr = (const float4*)(x + (size_t)row * D_MODEL);
    float4 v = xr[tid];
    float s  = v.x + v.y + v.z + v.w;
    float sq = v.x*v.x + v.y*v.y + v.z*v.z + v.w*v.w;
    #pragma unroll
    for (int off = 32; off > 0; off >>= 1) {
        s  += __shfl_down(s,  off, 64);
        sq += __shfl_down(sq, off, 64);
    }
    __shared__ float ls[4], lq[4];
    int wave = tid >> 6, lane = tid & 63;
    if (lane == 0) { ls[wave] = s; lq[wave] = sq; }
    __syncthreads();
    s  = ls[0] + ls[1] + ls[2] + ls[3];
    sq = lq[0] + lq[1] + lq[2] + lq[3];
    float mu  = s * (1.f / D_MODEL);
    float var = sq * (1.f / D_MODEL) - mu * mu;
    float rs  = rsqrtf(var + EPS);
    float4 g  = ((const float4*)gamma)[tid];
    float4 bb = ((const float4*)beta)[tid];
    ushort4 o;
    o.x = f2bf((v.x - mu) * rs * g.x + bb.x);
    o.y = f2bf((v.y - mu) * rs * g.y + bb.y);
    o.z = f2bf((v.z - mu) * rs * g.z + bb.z);
    o.w = f2bf((v.w - mu) * rs * g.w + bb.w);
    ((ushort4*)(out + (size_t)row * D_MODEL))[tid] = o;
}

// ---------------- transpose fp32 [R][C] -> bf16 [C_pad][R] (pad rows zero) ----
__global__ __launch_bounds__(256) void transpose_bf16(
    const float* __restrict__ in, unsigned short* __restrict__ out,
    int R, int C)
{
    __shared__ float tile[32][33];
    int c0 = blockIdx.x * 32;
    int r0 = blockIdx.y * 32;
    int tx = threadIdx.x & 31;
    int ty = threadIdx.x >> 5;   // 0..7
    #pragma unroll
    for (int i = 0; i < 4; ++i) {
        int r = ty + i * 8;
        int gc = c0 + tx;
        tile[r][tx] = (gc < C) ? in[(size_t)(r0 + r) * C + gc] : 0.f;
    }
    __syncthreads();
    #pragma unroll
    for (int i = 0; i < 4; ++i) {
        int oc = ty + i * 8;     // output row offset within tile
        out[(size_t)(c0 + oc) * R + r0 + tx] = f2bf(tile[tx][oc]);
    }
}

// ---------------- bf16 MFMA GEMM (m97 structure) ----------------
// A: [M][K] bf16 row-major.  BT: [Ntiles*BN][K] bf16 (B transposed, zero-padded).
// C: fp32 [M][Nstride], stores guarded col<Nreal. 256 thr = 4 waves (2x2).
template<int BM, int BN, bool HAS_ADD, bool GUARD_N>
__global__ __launch_bounds__(256) void gemm_bf16(
    const unsigned short* __restrict__ A, const unsigned short* __restrict__ BT,
    const float* __restrict__ bias, const float* __restrict__ add,
    float* __restrict__ C, int Nreal, int Nstride, int K)
{
    constexpr int FM = BM / 32;       // fragments per wave (M)
    constexpr int FN = BN / 32;
    __shared__ unsigned short Asm[BM * 32];
    __shared__ unsigned short Bsm[BN * 32];
    const int tid = threadIdx.x;
    const int l = tid & 63, w = tid >> 6;
    const int lr = l & 15, lk = l >> 4;
    const int m0 = blockIdx.y * BM, n0 = blockIdx.x * BN;
    const int wm = w >> 1, wn = w & 1;

    f32x4 acc[FM][FN] = {};

    const unsigned short* Abase = A  + (size_t)(m0 + lr) * K + lk * 8;
    const unsigned short* Bbase = BT + (size_t)(n0 + lr) * K + lk * 8;

    for (int k0 = 0; k0 < K; k0 += 32) {
        #pragma unroll
        for (int i = 0; i < BM / 64; ++i) {
            int mb = w + 4 * i;
            __builtin_amdgcn_global_load_lds(
                GLB_AS(Abase + (size_t)mb * 16 * K + k0),
                LDS_AS(&Asm[mb * 512]), 16, 0, 0);
        }
        #pragma unroll
        for (int i = 0; i < BN / 64; ++i) {
            int nb = w + 4 * i;
            __builtin_amdgcn_global_load_lds(
                GLB_AS(Bbase + (size_t)nb * 16 * K + k0),
                LDS_AS(&Bsm[nb * 512]), 16, 0, 0);
        }
        __syncthreads();
        s16x8 af[FM], bfv[FN];
        #pragma unroll
        for (int i = 0; i < FM; ++i)
            af[i] = *(const s16x8*)&Asm[((wm * FM + i) * 64 + l) * 8];
        #pragma unroll
        for (int j = 0; j < FN; ++j)
            bfv[j] = *(const s16x8*)&Bsm[((wn * FN + j) * 64 + l) * 8];
        #pragma unroll
        for (int i = 0; i < FM; ++i)
            #pragma unroll
            for (int j = 0; j < FN; ++j)
                acc[i][j] = __builtin_amdgcn_mfma_f32_16x16x32_bf16(
                    af[i], bfv[j], acc[i][j], 0, 0, 0);
        __syncthreads();
    }

    #pragma unroll
    for (int i = 0; i < FM; ++i) {
        int row = m0 + (wm * FM + i) * 16 + lk * 4;
        #pragma unroll
        for (int j = 0; j < FN; ++j) {
            int col = n0 + (wn * FN + j) * 16 + lr;
            if (GUARD_N && col >= Nreal) continue;
            float bv = bias[col];
            #pragma unroll
            for (int r = 0; r < 4; ++r) {
                float v = acc[i][j][r] + bv;
                if (HAS_ADD) v += add[(size_t)(row + r) * Nstride + col];
                C[(size_t)(row + r) * Nstride + col] = v;
            }
        }
    }
}

// ================= chunked scan (fp32 in, bf16 gated-y out) =================
__global__ __launch_bounds__(256) void scan_pass1(
    const float* __restrict__ zx, const float* __restrict__ A_log,
    const float* __restrict__ dt_bias,
    float* __restrict__ Sbuf, float* __restrict__ Dk)
{
    int blk = blockIdx.x;
    int bh = blk / NCH, ck = blk % NCH;
    int b = bh >> 3, h = bh & 7;
    int p = threadIdx.x;
    float a   = -expf(A_log[h]);
    float dtb = dt_bias[h];

    float hs[STATE];
    #pragma unroll
    for (int n = 0; n < STATE; ++n) hs[n] = 0.f;
    float dtsum = 0.f;

    int t0 = ck * QCHUNK;
    for (int tt = 0; tt < QCHUNK; ++tt) {
        const float* row = zx + (size_t)(b * SEQ + t0 + tt) * PROJ_OUT;
        float dtr = row[2 * INNER + 2 * STATE + h] + dtb;
        float dt  = (dtr > 20.f) ? dtr : log1pf(expf(dtr));
        float dec = expf(dt * a);
        dtsum += dt;
        float x   = row[INNER + h * HEAD_DIM + p];
        float dtx = dt * x;
        #pragma unroll
        for (int n = 0; n < STATE; ++n)
            hs[n] = dec * hs[n] + dtx * row[2 * INNER + n];
    }
    float* sp = Sbuf + ((size_t)bh * NCH + ck) * (STATE * HEAD_DIM);
    #pragma unroll
    for (int n = 0; n < STATE; ++n)
        sp[n * HEAD_DIM + p] = hs[n];
    if (p == 0) Dk[bh * NCH + ck] = expf(dtsum * a);
}

__global__ __launch_bounds__(256) void scan_combine(
    float* __restrict__ Sbuf, const float* __restrict__ Dk)
{
    int bh = blockIdx.y;
    int e  = blockIdx.x * 256 + threadIdx.x;
    size_t base = (size_t)bh * NCH * (STATE * HEAD_DIM) + e;
    float h = 0.f;
    #pragma unroll
    for (int k = 0; k < NCH; ++k) {
        size_t idx = base + (size_t)k * (STATE * HEAD_DIM);
        float s = Sbuf[idx];
        Sbuf[idx] = h;
        h = Dk[bh * NCH + k] * h + s;
    }
}

__global__ __launch_bounds__(256) void scan_pass2(
    const float* __restrict__ zx, const float* __restrict__ A_log,
    const float* __restrict__ D_skip, const float* __restrict__ dt_bias,
    const float* __restrict__ Sbuf, unsigned short* __restrict__ yg)
{
    int blk = blockIdx.x;
    int bh = blk / NCH, ck = blk % NCH;
    int b = bh >> 3, h = bh & 7;
    int p = threadIdx.x;
    float a   = -expf(A_log[h]);
    float dsk = D_skip[h];
    float dtb = dt_bias[h];

    const float* sp = Sbuf + ((size_t)bh * NCH + ck) * (STATE * HEAD_DIM);
    float hs[STATE];
    #pragma unroll
    for (int n = 0; n < STATE; ++n) hs[n] = sp[n * HEAD_DIM + p];

    int t0 = ck * QCHUNK;
    for (int tt = 0; tt < QCHUNK; ++tt) {
        const float* row = zx + (size_t)(b * SEQ + t0 + tt) * PROJ_OUT;
        float dtr = row[2 * INNER + 2 * STATE + h] + dtb;
        float dt  = (dtr > 20.f) ? dtr : log1pf(expf(dtr));
        float dec = expf(dt * a);
        float x   = row[INNER + h * HEAD_DIM + p];
        float z   = row[h * HEAD_DIM + p];
        float dtx = dt * x;

        #pragma unroll
        for (int n = 0; n < STATE; ++n)
            hs[n] = dec * hs[n] + dtx * row[2 * INNER + n];

        float y0 = 0.f, y1 = 0.f, y2 = 0.f, y3 = 0.f;
        #pragma unroll
        for (int n = 0; n < STATE; n += 4) {
            y0 += hs[n + 0] * row[2 * INNER + STATE + n + 0];
            y1 += hs[n + 1] * row[2 * INNER + STATE + n + 1];
            y2 += hs[n + 2] * row[2 * INNER + STATE + n + 2];
            y3 += hs[n + 3] * row[2 * INNER + STATE + n + 3];
        }
        float y = (y0 + y1) + (y2 + y3) + dsk * x;
        float gate = z / (1.f + expf(-z));
        yg[(size_t)(b * SEQ + t0 + tt) * INNER + h * HEAD_DIM + p] = f2bf(y * gate);
    }
}

// ---------------- fallback serial scan (if ws too small) ----------------
__global__ __launch_bounds__(256) void scan_serial(
    const float* __restrict__ zx,
    const float* __restrict__ A_log, const float* __restrict__ D_skip,
    const float* __restrict__ dt_bias,
    unsigned short* __restrict__ yg)
{
    int bh = blockIdx.x;
    int b  = bh >> 3, h = bh & 7;
    int p  = threadIdx.x;
    float a   = -expf(A_log[h]);
    float dsk = D_skip[h];
    float dtb = dt_bias[h];

    float hs[STATE];
    #pragma unroll
    for (int n = 0; n < STATE; ++n) hs[n] = 0.f;

    for (int t = 0; t < SEQ; ++t) {
        const float* row = zx + (size_t)(b * SEQ + t) * PROJ_OUT;
        float dtr = row[2 * INNER + 2 * STATE + h] + dtb;
        float dt  = (dtr > 20.f) ? dtr : log1pf(expf(dtr));
        float dec = expf(dt * a);
        float x   = row[INNER + h * HEAD_DIM + p];
        float z   = row[h * HEAD_DIM + p];
        float dtx = dt * x;
        #pragma unroll
        for (int n = 0; n < STATE; ++n)
            hs[n] = dec * hs[n] + dtx * row[2 * INNER + n];
        float y0 = 0.f, y1 = 0.f, y2 = 0.f, y3 = 0.f;
        #pragma unroll
        for (int n = 0; n < STATE; n += 4) {
            y0 += hs[n + 0] * row[2 * INNER + STATE + n + 0];
            y1 += hs[n + 1] * row[2 * INNER + STATE + n + 1];
            y2 += hs[n + 2] * row[2 * INNER + STATE + n + 2];
            y3 += hs[n + 3] * row[2 * INNER + STATE + n + 3];
        }
        float y = (y0 + y1) + (y2 + y3) + dsk * x;
        float gate = z / (1.f + expf(-z));
        yg[(size_t)(b * SEQ + t) * INNER + h * HEAD_DIM + p] = f2bf(y * gate);
    }
}

extern "C" void kernel_launch(void* const* d_in, const int* in_sizes, int n_in,
                              void* d_out, int out_size, void* d_ws, size_t ws_size,
                              hipStream_t stream) {
    const float* input  = (const float*)d_in[0];
    const float* gamma  = (const float*)d_in[1];
    const float* beta   = (const float*)d_in[2];
    const float* W_in   = (const float*)d_in[3];
    const float* b_in   = (const float*)d_in[4];
    const float* A_log  = (const float*)d_in[5];
    const float* D_skip = (const float*)d_in[6];
    const float* dt_b   = (const float*)d_in[7];
    const float* W_out  = (const float*)d_in[8];
    const float* b_out  = (const float*)d_in[9];
    float* out = (float*)d_out;

    char* ws = (char*)d_ws;
    size_t off = 0;
    unsigned short* normed_bf = (unsigned short*)(ws + off); off += (size_t)NROWS * D_MODEL * 2;
    float*          zx        = (float*)(ws + off);          off += (size_t)NROWS * PROJ_OUT * 4;
    unsigned short* yg        = (unsigned short*)(ws + off); off += (size_t)NROWS * INNER * 2;
    unsigned short* WT        = (unsigned short*)(ws + off); off += (size_t)NPAD * D_MODEL * 2;
    unsigned short* WoT       = (unsigned short*)(ws + off); off += (size_t)D_MODEL * INNER * 2;
    size_t off_nosbuf = off;
    float*          Sbuf      = (float*)(ws + off);          off += (size_t)BH * NCH * STATE * HEAD_DIM * 4;
    float*          Dk        = (float*)(ws + off);          off += (size_t)BH * NCH * 4;
    bool chunked = (off <= ws_size);
    (void)off_nosbuf;

    // weight transposes -> bf16 [N][K]
    dim3 gt1(NPAD / 32, D_MODEL / 32);
    transpose_bf16<<<gt1, 256, 0, stream>>>(W_in, WT, D_MODEL, PROJ_OUT);
    dim3 gt2(D_MODEL / 32, INNER / 32);
    transpose_bf16<<<gt2, 256, 0, stream>>>(W_out, WoT, INNER, D_MODEL);

    ln_kernel<<<NROWS, 256, 0, stream>>>(input, gamma, beta, normed_bf);

    // GEMM1: [2048x1024] @ [1024x4232] -> zx fp32 (stride 4232, 34 col tiles)
    dim3 g1(NPAD / 128, NROWS / 128);
    gemm_bf16<128, 128, false, true><<<g1, 256, 0, stream>>>(
        normed_bf, WT, b_in, nullptr, zx, PROJ_OUT, PROJ_OUT, D_MODEL);

    if (chunked) {
        scan_pass1<<<BH * NCH, 256, 0, stream>>>(zx, A_log, dt_b, Sbuf, Dk);
        dim3 gc(STATE * HEAD_DIM / 256, BH);
        scan_combine<<<gc, 256, 0, stream>>>(Sbuf, Dk);
        scan_pass2<<<BH * NCH, 256, 0, stream>>>(zx, A_log, D_skip, dt_b, Sbuf, yg);
    } else {
        scan_serial<<<BH, 256, 0, stream>>>(zx, A_log, D_skip, dt_b, yg);
    }

    // GEMM2: [2048x2048] @ [2048x1024] + input -> out fp32
    dim3 g2(D_MODEL / 64, NROWS / 128);
    gemm_bf16<128, 64, true, false><<<g2, 256, 0, stream>>>(
        yg, WoT, b_out, input, out, D_MODEL, D_MODEL, INNER);
}

// Round 4
// 218.140 us; speedup vs baseline: 10.0719x; 1.3763x over previous
//
#include <hip/hip_runtime.h>
#include <math.h>

#define D_MODEL 1024
#define STATE 64
#define HEADS 8
#define INNER 2048
#define HEAD_DIM 256
#define PROJ_OUT 4232   // 2*INNER + 2*STATE + HEADS
#define NPAD 4352       // 34*128
#define BATCH 2
#define SEQ 1024
#define NROWS (BATCH*SEQ)
#define EPS 1e-5f
#define BH (BATCH * HEADS)      // 16

typedef short s16x8 __attribute__((ext_vector_type(8)));
typedef float f32x4 __attribute__((ext_vector_type(4)));

#define LDS_AS(p) ((__attribute__((address_space(3))) void*)(p))
#define GLB_AS(p) ((const __attribute__((address_space(1))) void*)(p))

__device__ inline unsigned short f2bf(float f) {
    unsigned int u = __float_as_uint(f);
    unsigned int r = (u + 0x7fffu + ((u >> 16) & 1u)) >> 16;
    return (unsigned short)r;
}

// ---------------- LayerNorm -> bf16 ----------------
__global__ __launch_bounds__(256) void ln_kernel(
    const float* __restrict__ x, const float* __restrict__ gamma,
    const float* __restrict__ beta, unsigned short* __restrict__ out)
{
    int row = blockIdx.x;
    int tid = threadIdx.x;
    const float4* xr = (const float4*)(x + (size_t)row * D_MODEL);
    float4 v = xr[tid];
    float s  = v.x + v.y + v.z + v.w;
    float sq = v.x*v.x + v.y*v.y + v.z*v.z + v.w*v.w;
    #pragma unroll
    for (int off = 32; off > 0; off >>= 1) {
        s  += __shfl_down(s,  off, 64);
        sq += __shfl_down(sq, off, 64);
    }
    __shared__ float ls[4], lq[4];
    int wave = tid >> 6, lane = tid & 63;
    if (lane == 0) { ls[wave] = s; lq[wave] = sq; }
    __syncthreads();
    s  = ls[0] + ls[1] + ls[2] + ls[3];
    sq = lq[0] + lq[1] + lq[2] + lq[3];
    float mu  = s * (1.f / D_MODEL);
    float var = sq * (1.f / D_MODEL) - mu * mu;
    float rs  = rsqrtf(var + EPS);
    float4 g  = ((const float4*)gamma)[tid];
    float4 bb = ((const float4*)beta)[tid];
    ushort4 o;
    o.x = f2bf((v.x - mu) * rs * g.x + bb.x);
    o.y = f2bf((v.y - mu) * rs * g.y + bb.y);
    o.z = f2bf((v.z - mu) * rs * g.z + bb.z);
    o.w = f2bf((v.w - mu) * rs * g.w + bb.w);
    ((ushort4*)(out + (size_t)row * D_MODEL))[tid] = o;
}

// ---------------- transpose fp32 [R][C] -> bf16 [C_pad][R] ----------------
__global__ __launch_bounds__(256) void transpose_bf16(
    const float* __restrict__ in, unsigned short* __restrict__ out,
    int R, int C)
{
    __shared__ float tile[32][33];
    int c0 = blockIdx.x * 32;
    int r0 = blockIdx.y * 32;
    int tx = threadIdx.x & 31;
    int ty = threadIdx.x >> 5;
    #pragma unroll
    for (int i = 0; i < 4; ++i) {
        int r = ty + i * 8;
        int gc = c0 + tx;
        tile[r][tx] = (gc < C) ? in[(size_t)(r0 + r) * C + gc] : 0.f;
    }
    __syncthreads();
    #pragma unroll
    for (int i = 0; i < 4; ++i) {
        int oc = ty + i * 8;
        out[(size_t)(c0 + oc) * R + r0 + tx] = f2bf(tile[tx][oc]);
    }
}

// ---------------- bf16 MFMA GEMM (m97 structure) ----------------
template<int BM, int BN, bool HAS_ADD, bool GUARD_N>
__global__ __launch_bounds__(256) void gemm_bf16(
    const unsigned short* __restrict__ A, const unsigned short* __restrict__ BT,
    const float* __restrict__ bias, const float* __restrict__ add,
    float* __restrict__ C, int Nreal, int Nstride, int K)
{
    constexpr int FM = BM / 32;
    constexpr int FN = BN / 32;
    __shared__ unsigned short Asm[BM * 32];
    __shared__ unsigned short Bsm[BN * 32];
    const int tid = threadIdx.x;
    const int l = tid & 63, w = tid >> 6;
    const int lr = l & 15, lk = l >> 4;
    const int m0 = blockIdx.y * BM, n0 = blockIdx.x * BN;
    const int wm = w >> 1, wn = w & 1;

    f32x4 acc[FM][FN] = {};

    const unsigned short* Abase = A  + (size_t)(m0 + lr) * K + lk * 8;
    const unsigned short* Bbase = BT + (size_t)(n0 + lr) * K + lk * 8;

    for (int k0 = 0; k0 < K; k0 += 32) {
        #pragma unroll
        for (int i = 0; i < BM / 64; ++i) {
            int mb = w + 4 * i;
            __builtin_amdgcn_global_load_lds(
                GLB_AS(Abase + (size_t)mb * 16 * K + k0),
                LDS_AS(&Asm[mb * 512]), 16, 0, 0);
        }
        #pragma unroll
        for (int i = 0; i < BN / 64; ++i) {
            int nb = w + 4 * i;
            __builtin_amdgcn_global_load_lds(
                GLB_AS(Bbase + (size_t)nb * 16 * K + k0),
                LDS_AS(&Bsm[nb * 512]), 16, 0, 0);
        }
        __syncthreads();
        s16x8 af[FM], bfv[FN];
        #pragma unroll
        for (int i = 0; i < FM; ++i)
            af[i] = *(const s16x8*)&Asm[((wm * FM + i) * 64 + l) * 8];
        #pragma unroll
        for (int j = 0; j < FN; ++j)
            bfv[j] = *(const s16x8*)&Bsm[((wn * FN + j) * 64 + l) * 8];
        #pragma unroll
        for (int i = 0; i < FM; ++i)
            #pragma unroll
            for (int j = 0; j < FN; ++j)
                acc[i][j] = __builtin_amdgcn_mfma_f32_16x16x32_bf16(
                    af[i], bfv[j], acc[i][j], 0, 0, 0);
        __syncthreads();
    }

    #pragma unroll
    for (int i = 0; i < FM; ++i) {
        int row = m0 + (wm * FM + i) * 16 + lk * 4;
        #pragma unroll
        for (int j = 0; j < FN; ++j) {
            int col = n0 + (wn * FN + j) * 16 + lr;
            if (GUARD_N && col >= Nreal) continue;
            float bv = bias[col];
            #pragma unroll
            for (int r = 0; r < 4; ++r) {
                float v = acc[i][j][r] + bv;
                if (HAS_ADD) v += add[(size_t)(row + r) * Nstride + col];
                C[(size_t)(row + r) * Nstride + col] = v;
            }
        }
    }
}

// ================= chunked scan, templated chunk length =================
template<int LQ>
__global__ __launch_bounds__(256) void scan_pass1(
    const float* __restrict__ zx, const float* __restrict__ A_log,
    const float* __restrict__ dt_bias,
    float* __restrict__ Sbuf, float* __restrict__ Dk)
{
    constexpr int NCHq = SEQ / LQ;
    int blk = blockIdx.x;
    int bh = blk / NCHq, ck = blk % NCHq;
    int b = bh >> 3, h = bh & 7;
    int p = threadIdx.x;
    float a   = -expf(A_log[h]);
    float dtb = dt_bias[h];

    float hs[STATE];
    #pragma unroll
    for (int n = 0; n < STATE; ++n) hs[n] = 0.f;
    float dtsum = 0.f;

    int t0 = ck * LQ;
    for (int tt = 0; tt < LQ; ++tt) {
        const float* row = zx + (size_t)(b * SEQ + t0 + tt) * PROJ_OUT;
        float dtr = row[2 * INNER + 2 * STATE + h] + dtb;
        float dt  = (dtr > 20.f) ? dtr : log1pf(expf(dtr));
        float dec = expf(dt * a);
        dtsum += dt;
        float x   = row[INNER + h * HEAD_DIM + p];
        float dtx = dt * x;
        #pragma unroll
        for (int n = 0; n < STATE; ++n)
            hs[n] = dec * hs[n] + dtx * row[2 * INNER + n];
    }
    float* sp = Sbuf + ((size_t)bh * NCHq + ck) * (STATE * HEAD_DIM);
    #pragma unroll
    for (int n = 0; n < STATE; ++n)
        sp[n * HEAD_DIM + p] = hs[n];
    if (p == 0) Dk[bh * NCHq + ck] = expf(dtsum * a);
}

template<int NCHq>
__global__ __launch_bounds__(256) void scan_combine(
    float* __restrict__ Sbuf, const float* __restrict__ Dk)
{
    int bh = blockIdx.y;
    int e  = blockIdx.x * 256 + threadIdx.x;
    size_t base = (size_t)bh * NCHq * (STATE * HEAD_DIM) + e;
    float h = 0.f;
    #pragma unroll 8
    for (int k = 0; k < NCHq; ++k) {
        size_t idx = base + (size_t)k * (STATE * HEAD_DIM);
        float s = Sbuf[idx];
        Sbuf[idx] = h;
        h = Dk[bh * NCHq + k] * h + s;
    }
}

template<int LQ>
__global__ __launch_bounds__(256) void scan_pass2(
    const float* __restrict__ zx, const float* __restrict__ A_log,
    const float* __restrict__ D_skip, const float* __restrict__ dt_bias,
    const float* __restrict__ Sbuf, unsigned short* __restrict__ yg)
{
    constexpr int NCHq = SEQ / LQ;
    int blk = blockIdx.x;
    int bh = blk / NCHq, ck = blk % NCHq;
    int b = bh >> 3, h = bh & 7;
    int p = threadIdx.x;
    float a   = -expf(A_log[h]);
    float dsk = D_skip[h];
    float dtb = dt_bias[h];

    const float* sp = Sbuf + ((size_t)bh * NCHq + ck) * (STATE * HEAD_DIM);
    float hs[STATE];
    #pragma unroll
    for (int n = 0; n < STATE; ++n) hs[n] = sp[n * HEAD_DIM + p];

    int t0 = ck * LQ;
    for (int tt = 0; tt < LQ; ++tt) {
        const float* row = zx + (size_t)(b * SEQ + t0 + tt) * PROJ_OUT;
        float dtr = row[2 * INNER + 2 * STATE + h] + dtb;
        float dt  = (dtr > 20.f) ? dtr : log1pf(expf(dtr));
        float dec = expf(dt * a);
        float x   = row[INNER + h * HEAD_DIM + p];
        float z   = row[h * HEAD_DIM + p];
        float dtx = dt * x;

        #pragma unroll
        for (int n = 0; n < STATE; ++n)
            hs[n] = dec * hs[n] + dtx * row[2 * INNER + n];

        float y0 = 0.f, y1 = 0.f, y2 = 0.f, y3 = 0.f;
        #pragma unroll
        for (int n = 0; n < STATE; n += 4) {
            y0 += hs[n + 0] * row[2 * INNER + STATE + n + 0];
            y1 += hs[n + 1] * row[2 * INNER + STATE + n + 1];
            y2 += hs[n + 2] * row[2 * INNER + STATE + n + 2];
            y3 += hs[n + 3] * row[2 * INNER + STATE + n + 3];
        }
        float y = (y0 + y1) + (y2 + y3) + dsk * x;
        float gate = z / (1.f + expf(-z));
        yg[(size_t)(b * SEQ + t0 + tt) * INNER + h * HEAD_DIM + p] = f2bf(y * gate);
    }
}

// ---------------- fallback serial scan ----------------
__global__ __launch_bounds__(256) void scan_serial(
    const float* __restrict__ zx,
    const float* __restrict__ A_log, const float* __restrict__ D_skip,
    const float* __restrict__ dt_bias,
    unsigned short* __restrict__ yg)
{
    int bh = blockIdx.x;
    int b  = bh >> 3, h = bh & 7;
    int p  = threadIdx.x;
    float a   = -expf(A_log[h]);
    float dsk = D_skip[h];
    float dtb = dt_bias[h];

    float hs[STATE];
    #pragma unroll
    for (int n = 0; n < STATE; ++n) hs[n] = 0.f;

    for (int t = 0; t < SEQ; ++t) {
        const float* row = zx + (size_t)(b * SEQ + t) * PROJ_OUT;
        float dtr = row[2 * INNER + 2 * STATE + h] + dtb;
        float dt  = (dtr > 20.f) ? dtr : log1pf(expf(dtr));
        float dec = expf(dt * a);
        float x   = row[INNER + h * HEAD_DIM + p];
        float z   = row[h * HEAD_DIM + p];
        float dtx = dt * x;
        #pragma unroll
        for (int n = 0; n < STATE; ++n)
            hs[n] = dec * hs[n] + dtx * row[2 * INNER + n];
        float y0 = 0.f, y1 = 0.f, y2 = 0.f, y3 = 0.f;
        #pragma unroll
        for (int n = 0; n < STATE; n += 4) {
            y0 += hs[n + 0] * row[2 * INNER + STATE + n + 0];
            y1 += hs[n + 1] * row[2 * INNER + STATE + n + 1];
            y2 += hs[n + 2] * row[2 * INNER + STATE + n + 2];
            y3 += hs[n + 3] * row[2 * INNER + STATE + n + 3];
        }
        float y = (y0 + y1) + (y2 + y3) + dsk * x;
        float gate = z / (1.f + expf(-z));
        yg[(size_t)(b * SEQ + t) * INNER + h * HEAD_DIM + p] = f2bf(y * gate);
    }
}

extern "C" void kernel_launch(void* const* d_in, const int* in_sizes, int n_in,
                              void* d_out, int out_size, void* d_ws, size_t ws_size,
                              hipStream_t stream) {
    const float* input  = (const float*)d_in[0];
    const float* gamma  = (const float*)d_in[1];
    const float* beta   = (const float*)d_in[2];
    const float* W_in   = (const float*)d_in[3];
    const float* b_in   = (const float*)d_in[4];
    const float* A_log  = (const float*)d_in[5];
    const float* D_skip = (const float*)d_in[6];
    const float* dt_b   = (const float*)d_in[7];
    const float* W_out  = (const float*)d_in[8];
    const float* b_out  = (const float*)d_in[9];
    float* out = (float*)d_out;

    char* ws = (char*)d_ws;
    size_t off = 0;
    unsigned short* normed_bf = (unsigned short*)(ws + off); off += (size_t)NROWS * D_MODEL * 2;
    float*          zx        = (float*)(ws + off);          off += (size_t)NROWS * PROJ_OUT * 4;
    unsigned short* yg        = (unsigned short*)(ws + off); off += (size_t)NROWS * INNER * 2;
    unsigned short* WT        = (unsigned short*)(ws + off); off += (size_t)NPAD * D_MODEL * 2;
    unsigned short* WoT       = (unsigned short*)(ws + off); off += (size_t)D_MODEL * INNER * 2;
    float*          Sbuf      = (float*)(ws + off);
    // chunk-size ladder by available workspace
    auto sbuf_bytes = [](int nch) {
        return (size_t)BH * nch * STATE * HEAD_DIM * 4 + (size_t)BH * nch * 4;
    };
    int nch = 0;
    if      (off + sbuf_bytes(64) <= ws_size) nch = 64;
    else if (off + sbuf_bytes(32) <= ws_size) nch = 32;
    else if (off + sbuf_bytes(16) <= ws_size) nch = 16;
    float* Dk = Sbuf + (size_t)BH * (nch ? nch : 1) * STATE * HEAD_DIM;

    // weight transposes -> bf16 [N][K]
    dim3 gt1(NPAD / 32, D_MODEL / 32);
    transpose_bf16<<<gt1, 256, 0, stream>>>(W_in, WT, D_MODEL, PROJ_OUT);
    dim3 gt2(D_MODEL / 32, INNER / 32);
    transpose_bf16<<<gt2, 256, 0, stream>>>(W_out, WoT, INNER, D_MODEL);

    ln_kernel<<<NROWS, 256, 0, stream>>>(input, gamma, beta, normed_bf);

    dim3 g1(NPAD / 128, NROWS / 128);
    gemm_bf16<128, 128, false, true><<<g1, 256, 0, stream>>>(
        normed_bf, WT, b_in, nullptr, zx, PROJ_OUT, PROJ_OUT, D_MODEL);

    dim3 gc(STATE * HEAD_DIM / 256, BH);
    if (nch == 64) {
        scan_pass1<16><<<BH * 64, 256, 0, stream>>>(zx, A_log, dt_b, Sbuf, Dk);
        scan_combine<64><<<gc, 256, 0, stream>>>(Sbuf, Dk);
        scan_pass2<16><<<BH * 64, 256, 0, stream>>>(zx, A_log, D_skip, dt_b, Sbuf, yg);
    } else if (nch == 32) {
        scan_pass1<32><<<BH * 32, 256, 0, stream>>>(zx, A_log, dt_b, Sbuf, Dk);
        scan_combine<32><<<gc, 256, 0, stream>>>(Sbuf, Dk);
        scan_pass2<32><<<BH * 32, 256, 0, stream>>>(zx, A_log, D_skip, dt_b, Sbuf, yg);
    } else if (nch == 16) {
        scan_pass1<64><<<BH * 16, 256, 0, stream>>>(zx, A_log, dt_b, Sbuf, Dk);
        scan_combine<16><<<gc, 256, 0, stream>>>(Sbuf, Dk);
        scan_pass2<64><<<BH * 16, 256, 0, stream>>>(zx, A_log, D_skip, dt_b, Sbuf, yg);
    } else {
        scan_serial<<<BH, 256, 0, stream>>>(zx, A_log, D_skip, dt_b, yg);
    }

    dim3 g2(D_MODEL / 64, NROWS / 128);
    gemm_bf16<128, 64, true, false><<<g2, 256, 0, stream>>>(
        yg, WoT, b_out, input, out, D_MODEL, D_MODEL, INNER);
}